// Round 1
// baseline (549.356 us; speedup 1.0000x reference)
//
#include <hip/hip_runtime.h>
#include <math.h>

#define TLEN 96000
#define NFFT 640
#define HOP  320
#define NF   321
#define NT   301
#define FT   (NF * NT)   // 96621

#define TWO_PI_F 6.28318530717958647692f

// triu_indices(8), row-major
__constant__ int IU[36] = {0,0,0,0,0,0,0,0, 1,1,1,1,1,1,1, 2,2,2,2,2,2,
                           3,3,3,3,3, 4,4,4,4, 5,5,5, 6,6, 7};
__constant__ int JU[36] = {0,1,2,3,4,5,6,7, 1,2,3,4,5,6,7, 2,3,4,5,6,7,
                           3,4,5,6,7, 4,5,6,7, 5,6,7, 6,7, 7};

// ---------------------------------------------------------------------------
// K1: STFT of 17 signals (16 = x[b][c], 1 = ref_g batch 0).
// One block per (frame, signal). Uses n / n+320 fold: for even k only
// fr[n]+fr[n+320] contributes, for odd k only fr[n]-fr[n+320].
// Twiddles via in-register rotation recurrence (no LDS twiddle reads).
// Output layout: Sx[s][k][frame], refS[k][frame]  (float2 = re,im)
// ---------------------------------------------------------------------------
__global__ __launch_bounds__(320) void k_stft(const float* __restrict__ x,
                                              const float* __restrict__ ref_g,
                                              float2* __restrict__ Sx,
                                              float2* __restrict__ refS) {
    const int f   = blockIdx.x;   // 0..300
    const int s   = blockIdx.y;   // 0..16
    const int tid = threadIdx.x;  // 0..319
    __shared__ float fr[2][320];

    const float* sig = (s < 16) ? (x + (size_t)s * TLEN) : ref_g;
    {
        const int p0 = f * HOP + tid - HOP;      // sample for n = tid
        const int p1 = p0 + 320;                 // sample for n = tid+320
        const float c = cosf((TWO_PI_F / NFFT) * (float)tid);
        float v0 = (p0 >= 0 && p0 < TLEN) ? sig[p0] : 0.0f;
        float v1 = (p1 >= 0 && p1 < TLEN) ? sig[p1] : 0.0f;
        v0 *= (0.5f - 0.5f * c);                 // win[tid]
        v1 *= (0.5f + 0.5f * c);                 // win[tid+320]
        fr[0][tid] = v0 + v1;                    // used by even k
        fr[1][tid] = v0 - v1;                    // used by odd  k
    }
    __syncthreads();

    for (int k = tid; k <= 320; k += 320) {      // tid 0 also does k=320
        const float* fp = fr[k & 1];
        float sk, ck;
        sincosf(-(TWO_PI_F / NFFT) * (float)k, &sk, &ck);
        float cr = 1.0f, ci = 0.0f, ar = 0.0f, ai = 0.0f;
#pragma unroll 4
        for (int n = 0; n < 320; ++n) {
            const float v = fp[n];
            ar = fmaf(v, cr, ar);
            ai = fmaf(v, ci, ai);
            const float ncr = fmaf(-ci, sk, cr * ck);
            const float nci = fmaf( ci, ck, cr * sk);
            cr = ncr; ci = nci;
        }
        float2 o; o.x = ar; o.y = ai;
        if (s < 16) Sx[((size_t)s * NF + k) * NT + f] = o;
        else        refS[(size_t)k * NT + f] = o;
    }
}

// ---------------------------------------------------------------------------
// K2: covariance features.  feats[b][74][F][T].
// job 0..35: pair p -> channels 2p (re), 2p+1 (im); job 36: ref ch 72/73.
// cov = S_i * conj(S_j)
// ---------------------------------------------------------------------------
__global__ void k_cov(const float2* __restrict__ Sx, float* __restrict__ feats) {
    int idx = blockIdx.x * blockDim.x + threadIdx.x;
    if (idx >= 2 * 37 * FT) return;
    const int kt  = idx % FT;
    const int job = (idx / FT) % 37;
    const int b   = idx / (37 * FT);
    const float2* Sb = Sx + (size_t)b * 8 * FT;
    float* fb = feats + (size_t)b * 74 * FT;
    if (job == 36) {
        const float2 r = Sb[(size_t)3 * FT + kt];   // REF_CH = 3
        fb[(size_t)72 * FT + kt] = r.x;
        fb[(size_t)73 * FT + kt] = r.y;
    } else {
        const float2 a = Sb[(size_t)IU[job] * FT + kt];
        const float2 c = Sb[(size_t)JU[job] * FT + kt];
        fb[(size_t)(2 * job)     * FT + kt] = a.x * c.x + a.y * c.y;
        fb[(size_t)(2 * job + 1) * FT + kt] = a.y * c.x - a.x * c.y;
    }
}

// ---------------------------------------------------------------------------
// K3: deep filtering, batch 0 only.  est[m][f][t] = sum_k rtf_c * patches.
// patches[k=(ki,kj)][f][t] = refS[f+ki-1][t+kj-4] (0 outside).
// ---------------------------------------------------------------------------
__global__ void k_dfilter(const float2* __restrict__ rtf,
                          const float2* __restrict__ refS,
                          float2* __restrict__ est) {
    int idx = blockIdx.x * blockDim.x + threadIdx.x;
    if (idx >= 7 * FT) return;
    const int t = idx % NT;
    const int f = (idx / NT) % NF;
    const int m = idx / FT;
    float er = 0.0f, ei = 0.0f;
#pragma unroll
    for (int ki = 0; ki < 3; ++ki) {
        const int ff = f + ki - 1;
#pragma unroll
        for (int kj = 0; kj < 9; ++kj) {
            const int tt = t + kj - 4;
            float pr = 0.0f, pi = 0.0f;
            if ((unsigned)ff < (unsigned)NF && (unsigned)tt < (unsigned)NT) {
                const float2 p = refS[(size_t)ff * NT + tt];
                pr = p.x; pi = p.y;
            }
            const float2 r = rtf[(size_t)(((m * 3 + ki) * 9 + kj) * NF + f) * NT + t];
            er = fmaf(r.x, pr, er); er = fmaf(-r.y, pi, er);
            ei = fmaf(r.x, pi, ei); ei = fmaf( r.y, pr, ei);
        }
    }
    float2 o; o.x = er; o.y = ei;
    est[idx] = o;   // layout [m][f][t]
}

// ---------------------------------------------------------------------------
// K4: per-frame irfft(640) * win  ->  frames[m][frame][640].
// y[n]     = (1/640)(X0r + (-1)^n X320r + 2*sum_{k=1..319}(Xr ck - Xi sk))
// y[n+320] flips sign of odd-k terms.
// ---------------------------------------------------------------------------
__global__ __launch_bounds__(320) void k_iframes(const float2* __restrict__ est,
                                                 float* __restrict__ frames) {
    const int f   = blockIdx.x;  // frame
    const int m   = blockIdx.y;  // est channel
    const int tid = threadIdx.x; // n in [0,320)
    __shared__ float2 X[NF];
    for (int k = tid; k < NF; k += 320)
        X[k] = est[((size_t)m * NF + k) * NT + f];
    __syncthreads();

    const int n = tid;
    float s1, c1;
    sincosf((TWO_PI_F / NFFT) * (float)n, &s1, &c1);
    float cr = c1, ci = s1;          // (cos kφ, sin kφ) at k=1
    float accO = 0.0f, accE = 0.0f;
    for (int k = 1; k < 319; k += 2) {
        const float2 Xa = X[k];       // odd k
        accO = fmaf(Xa.x, cr, accO);
        accO = fmaf(-Xa.y, ci, accO);
        float ncr = fmaf(-ci, s1, cr * c1);
        float nci = fmaf( ci, c1, cr * s1);
        cr = ncr; ci = nci;
        const float2 Xb = X[k + 1];   // even k
        accE = fmaf(Xb.x, cr, accE);
        accE = fmaf(-Xb.y, ci, accE);
        ncr = fmaf(-ci, s1, cr * c1);
        nci = fmaf( ci, c1, cr * s1);
        cr = ncr; ci = nci;
    }
    {   // k = 319 (odd)
        const float2 Xa = X[319];
        accO = fmaf(Xa.x, cr, accO);
        accO = fmaf(-Xa.y, ci, accO);
    }
    const float sgn  = (n & 1) ? -1.0f : 1.0f;
    const float base = X[0].x + sgn * X[320].x;
    const float y1 = base + 2.0f * (accE + accO);   // sample n
    const float y2 = base + 2.0f * (accE - accO);   // sample n+320
    const float cw = cosf((TWO_PI_F / NFFT) * (float)n);
    const float w0 = 0.5f - 0.5f * cw;              // win[n]
    const float w1 = 0.5f + 0.5f * cw;              // win[n+320]
    const float inv = 1.0f / NFFT;
    float* fb = frames + ((size_t)m * NT + f) * NFFT;
    fb[n]       = y1 * inv * w0;
    fb[n + 320] = y2 * inv * w1;
}

// ---------------------------------------------------------------------------
// K5: overlap-add + wsum normalization + interleaved [t][c] output write.
// Valid t: exactly 2 frames overlap; wsum = w(n1)^2 + w(n1+320)^2.
// Channel 3 = ref_g (batch 0); others map to est channels.
// ---------------------------------------------------------------------------
__global__ void k_ola(const float* __restrict__ frames,
                      const float* __restrict__ ref_g,
                      float* __restrict__ out0) {
    int idx = blockIdx.x * blockDim.x + threadIdx.x;
    if (idx >= 8 * TLEN) return;
    const int c = idx & 7;
    const int t = idx >> 3;
    float o;
    if (c == 3) {
        o = ref_g[t];
    } else {
        const int m  = (c < 3) ? c : (c - 1);
        const int f1 = t / HOP + 1;          // in [1,300]
        const int n1 = t % HOP;
        const float a = frames[((size_t)m * NT + f1)     * NFFT + n1];
        const float b = frames[((size_t)m * NT + f1 - 1) * NFFT + n1 + 320];
        const float cw = cosf((TWO_PI_F / NFFT) * (float)n1);
        const float w0 = 0.5f - 0.5f * cw;
        const float w1 = 0.5f + 0.5f * cw;
        float ws = w0 * w0 + w1 * w1;
        ws = (ws > 1e-11f) ? ws : 1.0f;
        o = (a + b) / ws;
    }
    out0[idx] = o;
}

extern "C" void kernel_launch(void* const* d_in, const int* in_sizes, int n_in,
                              void* d_out, int out_size, void* d_ws, size_t ws_size,
                              hipStream_t stream) {
    const float* x     = (const float*)d_in[0];   // [2,8,96000]
    const float* rtf   = (const float*)d_in[1];   // [2,7,3,9,321,301,2]
    const float* ref_g = (const float*)d_in[2];   // [2,1,96000]

    float* out0  = (float*)d_out;                 // [96000,8]
    float* feats = (float*)d_out + (size_t)8 * TLEN;  // [2,74,321,301]

    // workspace carve-up (~24 MB total)
    float2* Sx     = (float2*)d_ws;                       // 16*FT float2
    float2* refS   = Sx + (size_t)16 * FT;                // FT float2
    float2* est    = refS + (size_t)FT;                   // 7*FT float2
    float*  frames = (float*)(est + (size_t)7 * FT);      // 7*301*640 floats

    k_stft<<<dim3(NT, 17), 320, 0, stream>>>(x, ref_g, Sx, refS);
    {
        const int total = 2 * 37 * FT;
        k_cov<<<(total + 255) / 256, 256, 0, stream>>>(Sx, feats);
    }
    {
        const int total = 7 * FT;
        k_dfilter<<<(total + 255) / 256, 256, 0, stream>>>(
            (const float2*)rtf, refS, est);
    }
    k_iframes<<<dim3(NT, 7), 320, 0, stream>>>(est, frames);
    {
        const int total = 8 * TLEN;
        k_ola<<<(total + 255) / 256, 256, 0, stream>>>(frames, ref_g, out0);
    }
}

// Round 2
// 457.669 us; speedup vs baseline: 1.2003x; 1.2003x over previous
//
#include <hip/hip_runtime.h>
#include <math.h>

#define TLEN 96000
#define NFFT 640
#define HOP  320
#define NF   321
#define NT   301
#define FT   (NF * NT)   // 96621

#define TWO_PI_F 6.28318530717958647692f

// triu_indices(8), row-major
__constant__ int IU[36] = {0,0,0,0,0,0,0,0, 1,1,1,1,1,1,1, 2,2,2,2,2,2,
                           3,3,3,3,3, 4,4,4,4, 5,5,5, 6,6, 7};
__constant__ int JU[36] = {0,1,2,3,4,5,6,7, 1,2,3,4,5,6,7, 2,3,4,5,6,7,
                           3,4,5,6,7, 4,5,6,7, 5,6,7, 6,7, 7};

// ---------------------------------------------------------------------------
// K1: STFT of 17 signals (16 = x[b][c], 1 = ref_g batch 0) via Goertzel.
// Fold n/n+320: even k sees fe = a[n]+a[n+320], odd k sees fo = a[n]-a[n+320].
// Thread t < 161 runs two real Goertzel chains: k=2t (on fe) and k=2t+1 (on fo)
// sharing one ds_read_b64 of ff[n] = (fe, fo).
// X_k = (-1)^k [(cosw*s1 - s2) + i sinw*s1],  w = 2*pi*k/640, N = 320 steps.
// ---------------------------------------------------------------------------
__global__ __launch_bounds__(192) void k_stft(const float* __restrict__ x,
                                              const float* __restrict__ ref_g,
                                              float2* __restrict__ Sx,
                                              float2* __restrict__ refS) {
    const int f   = blockIdx.x;   // 0..300 (frame)
    const int s   = blockIdx.y;   // 0..16  (signal)
    const int tid = threadIdx.x;  // 0..191

    __shared__ __align__(16) float2 ff[320];

    const float* sig = (s < 16) ? (x + (size_t)s * TLEN) : ref_g;
    for (int n = tid; n < 320; n += 192) {
        const int p0 = f * HOP + n - HOP;   // sample for window pos n
        const int p1 = p0 + 320;            // window pos n+320 (p1 >= 0 always)
        const float c = cosf((TWO_PI_F / NFFT) * (float)n);
        float v0 = (p0 >= 0 && p0 < TLEN) ? sig[p0] : 0.0f;
        float v1 = (p1 < TLEN) ? sig[p1] : 0.0f;
        v0 *= (0.5f - 0.5f * c);            // win[n]
        v1 *= (0.5f + 0.5f * c);            // win[n+320]
        float2 o; o.x = v0 + v1; o.y = v0 - v1;
        ff[n] = o;
    }
    __syncthreads();

    if (tid < 161) {
        const int ke = 2 * tid;          // even k: 0..320
        const int ko = ke + 1;           // odd  k: 1..319 (321 invalid, not stored)
        const float we = (TWO_PI_F / NFFT) * (float)ke;
        const float wo = (TWO_PI_F / NFFT) * (float)ko;
        const float c2e = 2.0f * cosf(we);
        const float c2o = 2.0f * cosf(wo);

        float se1 = 0.0f, se2 = 0.0f, so1 = 0.0f, so2 = 0.0f;
#pragma unroll 8
        for (int n = 0; n < 320; ++n) {
            const float2 v = ff[n];
            const float te = fmaf(c2e, se1, v.x - se2); se2 = se1; se1 = te;
            const float to = fmaf(c2o, so1, v.y - so2); so2 = so1; so1 = to;
        }

        float sE, cE; sincosf(we, &sE, &cE);
        float sO, cO; sincosf(wo, &sO, &cO);
        float2 Xe, Xo;
        Xe.x = cE * se1 - se2;            // (-1)^k = +1 for even k
        Xe.y = sE * se1;
        Xo.x = -(cO * so1 - so2);         // (-1)^k = -1 for odd k
        Xo.y = -(sO * so1);

        if (s < 16) {
            float2* base = Sx + (size_t)s * FT;
            base[(size_t)ke * NT + f] = Xe;
            if (ko < 320) base[(size_t)ko * NT + f] = Xo;
        } else {
            refS[(size_t)ke * NT + f] = Xe;
            if (ko < 320) refS[(size_t)ko * NT + f] = Xo;
        }
    }
}

// ---------------------------------------------------------------------------
// K2: covariance features.  feats[b][74][F][T].
// ---------------------------------------------------------------------------
__global__ void k_cov(const float2* __restrict__ Sx, float* __restrict__ feats) {
    int idx = blockIdx.x * blockDim.x + threadIdx.x;
    if (idx >= 2 * 37 * FT) return;
    const int kt  = idx % FT;
    const int job = (idx / FT) % 37;
    const int b   = idx / (37 * FT);
    const float2* Sb = Sx + (size_t)b * 8 * FT;
    float* fb = feats + (size_t)b * 74 * FT;
    if (job == 36) {
        const float2 r = Sb[(size_t)3 * FT + kt];   // REF_CH = 3
        fb[(size_t)72 * FT + kt] = r.x;
        fb[(size_t)73 * FT + kt] = r.y;
    } else {
        const float2 a = Sb[(size_t)IU[job] * FT + kt];
        const float2 c = Sb[(size_t)JU[job] * FT + kt];
        fb[(size_t)(2 * job)     * FT + kt] = a.x * c.x + a.y * c.y;
        fb[(size_t)(2 * job + 1) * FT + kt] = a.y * c.x - a.x * c.y;
    }
}

// ---------------------------------------------------------------------------
// K3: deep filtering, batch 0 only.  est[m][f][t] = sum_k rtf_c * patches.
// ---------------------------------------------------------------------------
__global__ void k_dfilter(const float2* __restrict__ rtf,
                          const float2* __restrict__ refS,
                          float2* __restrict__ est) {
    int idx = blockIdx.x * blockDim.x + threadIdx.x;
    if (idx >= 7 * FT) return;
    const int t = idx % NT;
    const int f = (idx / NT) % NF;
    const int m = idx / FT;
    float er = 0.0f, ei = 0.0f;
#pragma unroll
    for (int ki = 0; ki < 3; ++ki) {
        const int ff = f + ki - 1;
#pragma unroll
        for (int kj = 0; kj < 9; ++kj) {
            const int tt = t + kj - 4;
            float pr = 0.0f, pi = 0.0f;
            if ((unsigned)ff < (unsigned)NF && (unsigned)tt < (unsigned)NT) {
                const float2 p = refS[(size_t)ff * NT + tt];
                pr = p.x; pi = p.y;
            }
            const float2 r = rtf[(size_t)(((m * 3 + ki) * 9 + kj) * NF + f) * NT + t];
            er = fmaf(r.x, pr, er); er = fmaf(-r.y, pi, er);
            ei = fmaf(r.x, pi, ei); ei = fmaf( r.y, pr, ei);
        }
    }
    float2 o; o.x = er; o.y = ei;
    est[idx] = o;   // layout [m][f][t]
}

// ---------------------------------------------------------------------------
// K4: per-frame irfft(640)*win via Goertzel over k.
// Even/odd k split: PE = sum_{j=0..160} X_{2j} e^{i(2phi)j},
//                   PO = sum_{j=0..159} X_{2j+1} e^{i(2phi)j},  phi = 2*pi*n/640.
// e^{i*161*(2phi)} = (-1)^n e^{i*2*pi*n/320};  e^{i*160*(2phi)} = (-1)^n.
// y[n]     = (1/640)(2(Re PE + Re(e^{i phi} PO)) - X0r - (-1)^n X320r)
// y[n+320] = (1/640)(2(Re PE - Re(e^{i phi} PO)) - X0r - (-1)^n X320r)
// ---------------------------------------------------------------------------
__global__ __launch_bounds__(320) void k_iframes(const float2* __restrict__ est,
                                                 float* __restrict__ frames) {
    const int f   = blockIdx.x;  // frame
    const int m   = blockIdx.y;  // est channel
    const int tid = threadIdx.x; // n in [0,320)
    __shared__ __align__(16) float2 X[322];
    for (int k = tid; k < NF; k += 320)
        X[k] = est[((size_t)m * NF + k) * NT + f];
    if (tid == 0) { float2 z; z.x = 0.0f; z.y = 0.0f; X[321] = z; }
    __syncthreads();

    const int n = tid;
    float sp, cp; sincosf((TWO_PI_F / NFFT) * (float)n, &sp, &cp);  // e^{i phi}
    const float c2p = cp * cp - sp * sp;   // cos 2phi
    const float s2p = 2.0f * sp * cp;      // sin 2phi
    const float c2  = 2.0f * c2p;          // Goertzel coefficient

    float er1 = 0.0f, er2 = 0.0f, ei1 = 0.0f, ei2 = 0.0f;  // even chain (complex)
    float or1 = 0.0f, or2 = 0.0f, oi1 = 0.0f, oi2 = 0.0f;  // odd  chain (complex)
    const float4* Xp = (const float4*)X;
#pragma unroll 4
    for (int j = 0; j < 160; ++j) {
        const float4 v = Xp[j];   // (X_{2j}.re, X_{2j}.im, X_{2j+1}.re, X_{2j+1}.im)
        const float t0 = fmaf(c2, er1, v.x - er2); er2 = er1; er1 = t0;
        const float t1 = fmaf(c2, ei1, v.y - ei2); ei2 = ei1; ei1 = t1;
        const float t2 = fmaf(c2, or1, v.z - or2); or2 = or1; or1 = t2;
        const float t3 = fmaf(c2, oi1, v.w - oi2); oi2 = oi1; oi1 = t3;
    }
    {   // j = 160: even chain only (X[320])
        const float4 v = Xp[160];
        const float t0 = fmaf(c2, er1, v.x - er2); er2 = er1; er1 = t0;
        const float t1 = fmaf(c2, ei1, v.y - ei2); ei2 = ei1; ei1 = t1;
    }

    // base products: e^{-i 2phi} * s1 - s2   (e^{-iw} = c2p - i s2p)
    const float PEbr = c2p * er1 + s2p * ei1 - er2;
    const float PEbi = c2p * ei1 - s2p * er1 - ei2;
    const float PObr = c2p * or1 + s2p * oi1 - or2;
    const float PObi = c2p * oi1 - s2p * or1 - oi2;

    float sr, crr; sincosf((TWO_PI_F / 320.0f) * (float)n, &sr, &crr);
    const float sgn  = (n & 1) ? -1.0f : 1.0f;
    const float RePE = sgn * (crr * PEbr - sr * PEbi);
    const float RePO = sgn * (cp * PObr - sp * PObi);

    const float base = X[0].x + sgn * X[320].x;
    const float y1 = 2.0f * (RePE + RePO) - base;   // sample n
    const float y2 = 2.0f * (RePE - RePO) - base;   // sample n+320

    const float w0 = 0.5f - 0.5f * cp;              // win[n]   (cos(2 pi n/640) = cp)
    const float w1 = 0.5f + 0.5f * cp;              // win[n+320]
    const float inv = 1.0f / NFFT;
    float* fb = frames + ((size_t)m * NT + f) * NFFT;
    fb[n]       = y1 * inv * w0;
    fb[n + 320] = y2 * inv * w1;
}

// ---------------------------------------------------------------------------
// K5: overlap-add + wsum normalization + interleaved [t][c] output write.
// ---------------------------------------------------------------------------
__global__ void k_ola(const float* __restrict__ frames,
                      const float* __restrict__ ref_g,
                      float* __restrict__ out0) {
    int idx = blockIdx.x * blockDim.x + threadIdx.x;
    if (idx >= 8 * TLEN) return;
    const int c = idx & 7;
    const int t = idx >> 3;
    float o;
    if (c == 3) {
        o = ref_g[t];
    } else {
        const int m  = (c < 3) ? c : (c - 1);
        const int f1 = t / HOP + 1;          // in [1,300]
        const int n1 = t % HOP;
        const float a = frames[((size_t)m * NT + f1)     * NFFT + n1];
        const float b = frames[((size_t)m * NT + f1 - 1) * NFFT + n1 + 320];
        const float cw = cosf((TWO_PI_F / NFFT) * (float)n1);
        const float w0 = 0.5f - 0.5f * cw;
        const float w1 = 0.5f + 0.5f * cw;
        float ws = w0 * w0 + w1 * w1;
        ws = (ws > 1e-11f) ? ws : 1.0f;
        o = (a + b) / ws;
    }
    out0[idx] = o;
}

extern "C" void kernel_launch(void* const* d_in, const int* in_sizes, int n_in,
                              void* d_out, int out_size, void* d_ws, size_t ws_size,
                              hipStream_t stream) {
    const float* x     = (const float*)d_in[0];   // [2,8,96000]
    const float* rtf   = (const float*)d_in[1];   // [2,7,3,9,321,301,2]
    const float* ref_g = (const float*)d_in[2];   // [2,1,96000]

    float* out0  = (float*)d_out;                 // [96000,8]
    float* feats = (float*)d_out + (size_t)8 * TLEN;  // [2,74,321,301]

    // workspace carve-up (~24 MB total)
    float2* Sx     = (float2*)d_ws;                       // 16*FT float2
    float2* refS   = Sx + (size_t)16 * FT;                // FT float2
    float2* est    = refS + (size_t)FT;                   // 7*FT float2
    float*  frames = (float*)(est + (size_t)7 * FT);      // 7*301*640 floats

    k_stft<<<dim3(NT, 17), 192, 0, stream>>>(x, ref_g, Sx, refS);
    {
        const int total = 2 * 37 * FT;
        k_cov<<<(total + 255) / 256, 256, 0, stream>>>(Sx, feats);
    }
    {
        const int total = 7 * FT;
        k_dfilter<<<(total + 255) / 256, 256, 0, stream>>>(
            (const float2*)rtf, refS, est);
    }
    k_iframes<<<dim3(NT, 7), 320, 0, stream>>>(est, frames);
    {
        const int total = 8 * TLEN;
        k_ola<<<(total + 255) / 256, 256, 0, stream>>>(frames, ref_g, out0);
    }
}